// Round 1
// baseline (132.151 us; speedup 1.0000x reference)
//
#include <hip/hip_runtime.h>

#define TPB 256

__global__ __launch_bounds__(TPB) void fused_shift_conv(const float* __restrict__ x,
                                                        const float* __restrict__ Wg,
                                                        float* __restrict__ out) {
    // block handles one (n, p) output row-slab
    const int bid = blockIdx.x;
    const int p = bid % 56;
    const int n = bid / 56;
    const int P = (p + 55) % 56;   // source spatial row (circular roll by +1 along p)

    __shared__ float sm[64 * 57];  // t[r][col], r = 2g+m, padded stride 57 (odd -> spread banks)

    const int tid = threadIdx.x;

    // ---- stage: sm[r][col] = x[n, r, P, col] + x[n, r+64, P, col] ----
    // each x row (56 floats = 224B) is 16B-aligned -> 14 float4 per row, 64 rows = 896 f4
    {
        const float4* x4 = reinterpret_cast<const float4*>(x);
        for (int idx = tid; idx < 896; idx += TPB) {
            const int r = idx / 14;
            const int v = idx - r * 14;
            const size_t base = (size_t)(n * 128 + r) * 784 + (size_t)P * 14 + (size_t)v;
            const float4 a = x4[base];
            const float4 b = x4[base + (size_t)64 * 784];
            const int s = r * 57 + v * 4;
            sm[s + 0] = a.x + b.x;
            sm[s + 1] = a.y + b.y;
            sm[s + 2] = a.z + b.z;
            sm[s + 3] = a.w + b.w;
        }
    }
    __syncthreads();

    // ---- compute: thread owns channel c = j*4+k and o-half h ----
    const int h = tid & 1;
    const int c = tid >> 1;        // 0..127
    const int j = c >> 2;          // group 0..31
    const int k = c & 3;           // 0..3
    const int obase = h * 28;

    // 18 weights for this (j,k): W[j,i,m,l,k], shape (32,3,2,3,4). L2-resident.
    float wt[3][2][3];
#pragma unroll
    for (int i = 0; i < 3; ++i)
#pragma unroll
        for (int m = 0; m < 2; ++m)
#pragma unroll
            for (int l = 0; l < 3; ++l)
                wt[i][m][l] = Wg[(((j * 3 + i) * 2 + m) * 3 + l) * 4 + k];

    float acc[28];
#pragma unroll
    for (int u = 0; u < 28; ++u) acc[u] = 0.f;

#pragma unroll
    for (int i = 0; i < 3; ++i) {
        const int g = j + i - 1;                   // source group (zero-padded window)
        if ((unsigned)g < 32u) {
#pragma unroll
            for (int m = 0; m < 2; ++m) {
                const float* row = &sm[(2 * g + m) * 57];
                // val[d] = t[..., (obase + d - 2) mod 56]; tap l at output u reads val[u+l]
                float val[30];
#pragma unroll
                for (int d = 0; d < 30; ++d) {
                    int col = obase + d - 2;
                    col = (col < 0) ? col + 56 : (col >= 56 ? col - 56 : col);
                    val[d] = row[col];
                }
                // zero-pad masking: o=0,l=0 tap is val[0] (h==0); o=55,l=2 tap is val[29] (h==1)
                if (h == 0) val[0] = 0.f; else val[29] = 0.f;

                const float w0 = wt[i][m][0];
                const float w1 = wt[i][m][1];
                const float w2 = wt[i][m][2];
#pragma unroll
                for (int u = 0; u < 28; ++u)
                    acc[u] += w0 * val[u] + w1 * val[u + 1] + w2 * val[u + 2];
            }
        }
    }

    // ---- store: out[n, c, p, obase..obase+27], 7 aligned float4 ----
    float4* o4 = reinterpret_cast<float4*>(out);
    const size_t ob = (size_t)(n * 128 + c) * 784 + (size_t)p * 14 + (size_t)(h * 7);
#pragma unroll
    for (int q = 0; q < 7; ++q) {
        float4 v;
        v.x = acc[4 * q + 0];
        v.y = acc[4 * q + 1];
        v.z = acc[4 * q + 2];
        v.w = acc[4 * q + 3];
        o4[ob + q] = v;
    }
}

extern "C" void kernel_launch(void* const* d_in, const int* in_sizes, int n_in,
                              void* d_out, int out_size, void* d_ws, size_t ws_size,
                              hipStream_t stream) {
    const float* x = (const float*)d_in[0];
    const float* W = (const float*)d_in[1];
    float* out = (float*)d_out;
    const int n = in_sizes[0] / (128 * 56 * 56);   // 128
    const int grid = n * 56;                        // one block per (n, p)
    fused_shift_conv<<<grid, TPB, 0, stream>>>(x, W, out);
}

// Round 3
// 116.040 us; speedup vs baseline: 1.1388x; 1.1388x over previous
//
#include <hip/hip_runtime.h>

#define TPB 256

__global__ __launch_bounds__(TPB) void fused_shift_conv(const float* __restrict__ x,
                                                        const float* __restrict__ Wg,
                                                        float* __restrict__ out) {
    // block handles one (n, p) output row-slab
    const int bid = blockIdx.x;
    const int p = bid % 56;
    const int n = bid / 56;
    const int P = (p + 55) % 56;   // source spatial row (circular roll by +1 along p)

    __shared__ float sm[64 * 57];  // staging t[r][col]; later reused for output transpose

    const int tid = threadIdx.x;
    const int h = tid & 1;         // o-half: 0 -> o 0..27, 1 -> o 28..55
    const int c = tid >> 1;        // output channel 0..127
    const int j = c >> 2;          // group
    const int k = c & 3;

    // ---- W loads first: L2-resident, latency hides under x staging ----
    float wt[3][2][3];
#pragma unroll
    for (int i = 0; i < 3; ++i)
#pragma unroll
        for (int m = 0; m < 2; ++m)
#pragma unroll
            for (int l = 0; l < 3; ++l)
                wt[i][m][l] = Wg[(((j * 3 + i) * 2 + m) * 3 + l) * 4 + k];

    // ---- stage: sm[r][col] = x[n, r, P, col] + x[n, r+64, P, col] ----
    // x is (128,128,56,56) fp32; channel stride = 3136 floats = 784 float4.
    {
        const float4* x4 = reinterpret_cast<const float4*>(x);
#pragma unroll
        for (int it = 0; it < 4; ++it) {
            const int idx = tid + it * TPB;
            if (idx < 896) {
                const int r = idx / 14;
                const int v = idx - r * 14;
                const size_t base = (size_t)(n * 128 + r) * 784 + (size_t)P * 14 + (size_t)v;
                const float4 a = x4[base];
                const float4 b = x4[base + (size_t)64 * 784];
                const int s = r * 57 + v * 4;
                sm[s + 0] = a.x + b.x;
                sm[s + 1] = a.y + b.y;
                sm[s + 2] = a.z + b.z;
                sm[s + 3] = a.w + b.w;
            }
        }
    }
    __syncthreads();

    // ---- compute: 28 outputs per thread, linear LDS window (no modulo) ----
    // val[d] = t[(h*28 + d - 2) mod 56] with zero-pad masking:
    //   h=0: val[0]=0 (o=0,l=0 tap), val[1]=row[55] (circular), val[2..29]=row[0..27]
    //   h=1: val[0..28]=row[26..54], val[29]=0 (o=55,l=2 tap)
    const int sbase = h * 28 - 2;      // linear part: val[d] = row[sbase+d], d in 2..28
    const int sp1 = h ? 27 : 55;       // val[1] source

    float acc[28];
#pragma unroll
    for (int u = 0; u < 28; ++u) acc[u] = 0.f;

#pragma unroll
    for (int i = 0; i < 3; ++i) {
        const int g = j + i - 1;
        if ((unsigned)g < 32u) {
#pragma unroll
            for (int m = 0; m < 2; ++m) {
                const float* row = &sm[(2 * g + m) * 57];
                float val[30];
                const float v26 = row[26];
                const float v27 = row[27];
                val[0]  = h ? v26 : 0.f;
                val[1]  = row[sp1];
                val[29] = h ? 0.f : v27;
#pragma unroll
                for (int d = 2; d < 29; ++d) val[d] = row[sbase + d];

                const float w0 = wt[i][m][0];
                const float w1 = wt[i][m][1];
                const float w2 = wt[i][m][2];
#pragma unroll
                for (int u = 0; u < 28; ++u)
                    acc[u] += w0 * val[u] + w1 * val[u + 1] + w2 * val[u + 2];
            }
        }
    }

    // ---- 2-pass transposed store: reuse sm (64 rows per pass), coalesced 224B runs ----
    const int off = h * 28;
    const int chalf = c >> 6;      // which channel-half this thread owns
    const int crow = c & 63;
    float4* o4 = reinterpret_cast<float4*>(out);

#pragma unroll
    for (int half = 0; half < 2; ++half) {
        __syncthreads();           // sm free (compute reads / previous store done)
        if (chalf == half) {
            float* orow = &sm[crow * 57 + off];
#pragma unroll
            for (int u = 0; u < 28; ++u) orow[u] = acc[u];
        }
        __syncthreads();
#pragma unroll
        for (int it = 0; it < 4; ++it) {
            const int idx = tid + it * TPB;
            if (idx < 896) {
                const int r = idx / 14;
                const int v = idx - r * 14;
                const float* s = &sm[r * 57 + v * 4];
                float4 val4;
                val4.x = s[0]; val4.y = s[1]; val4.z = s[2]; val4.w = s[3];
                o4[(size_t)(n * 128 + half * 64 + r) * 784 + (size_t)p * 14 + (size_t)v] = val4;
            }
        }
    }
}

extern "C" void kernel_launch(void* const* d_in, const int* in_sizes, int n_in,
                              void* d_out, int out_size, void* d_ws, size_t ws_size,
                              hipStream_t stream) {
    const float* x = (const float*)d_in[0];
    const float* W = (const float*)d_in[1];
    float* out = (float*)d_out;
    const int n = in_sizes[0] / (128 * 56 * 56);   // 128
    const int grid = n * 56;                        // one block per (n, p)
    fused_shift_conv<<<grid, TPB, 0, stream>>>(x, W, out);
}

// Round 4
// 97.088 us; speedup vs baseline: 1.3611x; 1.1952x over previous
//
#include <hip/hip_runtime.h>

#define TPB 512

__global__ __launch_bounds__(TPB) void fused_shift_conv(const float* __restrict__ x,
                                                        const float* __restrict__ Wg,
                                                        float* __restrict__ out) {
    // block handles (n, p-tile of 2 output rows p0, p0+1)
    const int bid = blockIdx.x;
    const int ptile = bid % 28;
    const int n = bid / 28;
    const int p0 = ptile * 2;

    // source rows (circular roll +1 along p): output p0+pl reads row (p0+pl-1) mod 56
    const int P0 = (p0 + 55) % 56;
    const int P1 = p0;

    __shared__ float sm[2 * 64 * 57];   // staging: [r*2+pl][57]; reused as [ch][113] for output

    const int tid = threadIdx.x;
    const int pl = tid >> 8;            // 0..1 : which output row this thread computes
    const int t8 = tid & 255;
    const int h = t8 & 1;               // o-half: 0 -> o 0..27, 1 -> o 28..55
    const int c = t8 >> 1;              // output channel 0..127
    const int j = c >> 2;               // group
    const int k = c & 3;

    // ---- W loads first: L2-resident, latency hides under x staging ----
    float wt[3][2][3];
#pragma unroll
    for (int i = 0; i < 3; ++i)
#pragma unroll
        for (int m = 0; m < 2; ++m)
#pragma unroll
            for (int l = 0; l < 3; ++l)
                wt[i][m][l] = Wg[(((j * 3 + i) * 2 + m) * 3 + l) * 4 + k];

    // ---- stage: sm[(r*2+q)][col] = x[n, r, Pq, col] + x[n, r+64, Pq, col] ----
    // 2 x 64 rows x 14 float4 = 1792 float4 destinations; 448B contiguous runs per channel
    {
        const float4* x4 = reinterpret_cast<const float4*>(x);
#pragma unroll
        for (int it = 0; it < 4; ++it) {
            const int idx = tid + it * TPB;
            if (idx < 1792) {
                const int r = idx / 28;
                const int rem = idx - r * 28;
                const int q = rem / 14;         // staged row (source pl)
                const int v = rem - q * 14;
                const int Pr = q ? P1 : P0;
                const size_t base = (size_t)(n * 128 + r) * 784 + (size_t)Pr * 14 + (size_t)v;
                const float4 a = x4[base];
                const float4 b = x4[base + (size_t)64 * 784];
                const int s = (r * 2 + q) * 57 + v * 4;
                sm[s + 0] = a.x + b.x;
                sm[s + 1] = a.y + b.y;
                sm[s + 2] = a.z + b.z;
                sm[s + 3] = a.w + b.w;
            }
        }
    }
    __syncthreads();

    // ---- compute: 28 outputs per thread, linear LDS window (no modulo) ----
    //   h=0: val[0]=0 (o=0,l=0 tap), val[1]=row[55], val[2..28]=row[0..26], val[29]=row[27]
    //   h=1: val[0]=row[26], val[1]=row[27], val[2..28]=row[28..54], val[29]=0 (o=55,l=2)
    const int sbase = h * 28 - 2;
    const int sp1 = h ? 27 : 55;

    float acc[28];
#pragma unroll
    for (int u = 0; u < 28; ++u) acc[u] = 0.f;

#pragma unroll
    for (int i = 0; i < 3; ++i) {
        const int g = j + i - 1;
        if ((unsigned)g < 32u) {
#pragma unroll
            for (int m = 0; m < 2; ++m) {
                const float* row = &sm[((2 * g + m) * 2 + pl) * 57];
                float val[30];
                const float v26 = row[26];
                const float v27 = row[27];
                val[0]  = h ? v26 : 0.f;
                val[1]  = row[sp1];
                val[29] = h ? 0.f : v27;
#pragma unroll
                for (int d = 2; d < 29; ++d) val[d] = row[sbase + d];

                const float w0 = wt[i][m][0];
                const float w1 = wt[i][m][1];
                const float w2 = wt[i][m][2];
#pragma unroll
                for (int u = 0; u < 28; ++u)
                    acc[u] += w0 * val[u] + w1 * val[u + 1] + w2 * val[u + 2];
            }
        }
    }

    // ---- 2-pass transposed store via sm[ch][113] (odd pad -> conflict-free both sides) ----
    const int off = pl * 56 + h * 28;   // position within the 112-float channel run
    const int chalf = c >> 6;
    const int cr = c & 63;
    float2* o2 = reinterpret_cast<float2*>(out);

#pragma unroll
    for (int half = 0; half < 2; ++half) {
        __syncthreads();                 // sm free (compute reads / previous pass reads done)
        if (chalf == half) {
            float* orow = &sm[cr * 113 + off];
#pragma unroll
            for (int u = 0; u < 28; ++u) orow[u] = acc[u];
        }
        __syncthreads();
        // 64 ch x 112 floats = 3584 float2, exactly 7 per thread
#pragma unroll
        for (int it = 0; it < 7; ++it) {
            const int idx = tid + it * TPB;
            const int ch = idx / 56;         // local channel 0..63
            const int w2 = idx - ch * 56;    // float2 index within 112-float run
            float2 v2;
            v2.x = sm[ch * 113 + 2 * w2];
            v2.y = sm[ch * 113 + 2 * w2 + 1];
            // out[n, half*64+ch, p0 + (w/56), w%56] ; contiguous 448B per channel
            o2[(size_t)(n * 128 + half * 64 + ch) * 1568 + (size_t)p0 * 28 + (size_t)w2] = v2;
        }
    }
}

extern "C" void kernel_launch(void* const* d_in, const int* in_sizes, int n_in,
                              void* d_out, int out_size, void* d_ws, size_t ws_size,
                              hipStream_t stream) {
    const float* x = (const float*)d_in[0];
    const float* W = (const float*)d_in[1];
    float* out = (float*)d_out;
    const int n = in_sizes[0] / (128 * 56 * 56);   // 128
    const int grid = n * 28;                        // one block per (n, 2-row p-tile)
    fused_shift_conv<<<grid, TPB, 0, stream>>>(x, W, out);
}